// Round 4
// baseline (2836.819 us; speedup 1.0000x reference)
//
#include <hip/hip_runtime.h>

typedef __attribute__((ext_vector_type(8))) short short8;
typedef __attribute__((ext_vector_type(4))) float f32x4;

__device__ __forceinline__ float bf2f(ushort u) {
  union { unsigned int i; float f; } x; x.i = ((unsigned int)u) << 16; return x.f;
}
__device__ __forceinline__ ushort f2bf(float f) {
  union { float f; unsigned int i; } x; x.f = f;
  unsigned int i = x.i + 0x7fffu + ((x.i >> 16) & 1u);
  return (ushort)(i >> 16);
}
__device__ __forceinline__ float tanh_fast(float x) {
  return 1.f - 2.f / (__expf(2.f * x) + 1.f);
}
__device__ __forceinline__ void gload_lds16(const ushort* g, ushort* l) {
  __builtin_amdgcn_global_load_lds((const __attribute__((address_space(1))) void*)g,
                                   (__attribute__((address_space(3))) void*)l, 16, 0, 0);
}

// -------- fp32 -> bf16 bulk convert (8 elem/thread) --------
__global__ void f2b_vec(const float* __restrict__ in, ushort* __restrict__ out, int n) {
  int i = (blockIdx.x * blockDim.x + threadIdx.x) * 8;
  if (i >= n) return;
  f32x4 a = *(const f32x4*)(in + i);
  f32x4 b = *(const f32x4*)(in + i + 4);
  short8 o;
#pragma unroll
  for (int e = 0; e < 4; ++e) { o[e] = (short)f2bf(a[e]); o[e + 4] = (short)f2bf(b[e]); }
  *(short8*)(out + i) = o;
}

// -------- transpose fp32 -> bf16, out[c][r] = bf16(in[r][c]) --------
__global__ void transpose_f2b(const float* __restrict__ in, ushort* __restrict__ out,
                              int R, int C) {
  __shared__ ushort tile[32][33];
  int c0 = blockIdx.x * 32, r0 = blockIdx.y * 32;
  int tx = threadIdx.x, ty = threadIdx.y;  // block (32,8)
  for (int i = 0; i < 32; i += 8) {
    int r = r0 + ty + i, c = c0 + tx;
    if (r < R && c < C) tile[ty + i][tx] = f2bf(in[(size_t)r * C + c]);
  }
  __syncthreads();
  for (int i = 0; i < 32; i += 8) {
    int c = c0 + ty + i, r = r0 + tx;
    if (r < R && c < C) out[(size_t)c * R + r] = tile[tx][ty + i];
  }
}

// -------- gather embedded tokens (fp32 emb -> bf16): embA[t*128+b][:] --------
__global__ void embed_gather(const int* __restrict__ target, const float* __restrict__ emb,
                             ushort* __restrict__ embA) {
  int m = blockIdx.x;            // 0..6015
  int t = m >> 7, b = m & 127;
  int tok = (t == 0) ? 1 : target[b * 48 + t];
  embA[(size_t)m * 256 + threadIdx.x] = f2bf(emb[(size_t)tok * 256 + threadIdx.x]);
}

// ---------------- m97-style tiled GEMM: C = act(A[M,K]bf16 @ BT[Nrows,K]^T + bias) -------
// 128x128 tile, BK=32, global_load_lds staging, 4 waves each computing 64x64.
// flags: 1=relu, 2=store fp32, 4=remap rows m=t*128+b -> out row b*47+t
__global__ __launch_bounds__(256) void gemm_tile(
    const ushort* __restrict__ A, const ushort* __restrict__ BT,
    const float* __restrict__ bias, void* __restrict__ Cout,
    int M, int N, int K, int flags) {
  __shared__ ushort AL[128 * 32];
  __shared__ ushort BL[128 * 32];
  int wave = threadIdx.x >> 6, lane = threadIdx.x & 63;
  int q = lane >> 4, l16 = lane & 15;
  int m0 = blockIdx.y * 128, n0 = blockIdx.x * 128;
  int wr = wave >> 1, wc = wave & 1;
  int lrow = lane >> 2, lcol = (lane & 3) * 8;
  f32x4 acc[4][4];
#pragma unroll
  for (int i = 0; i < 4; ++i)
#pragma unroll
    for (int j = 0; j < 4; ++j) acc[i][j] = (f32x4){0.f, 0.f, 0.f, 0.f};
  for (int k = 0; k < K; k += 32) {
    __syncthreads();
#pragma unroll
    for (int i = 0; i < 2; ++i) {
      int r0 = wave * 32 + i * 16;
      gload_lds16(A + (size_t)(m0 + r0 + lrow) * K + k + lcol, &AL[r0 * 32]);
      gload_lds16(BT + (size_t)(n0 + r0 + lrow) * K + k + lcol, &BL[r0 * 32]);
    }
    __syncthreads();
    short8 af[4], bf[4];
#pragma unroll
    for (int i = 0; i < 4; ++i) af[i] = *(const short8*)&AL[(wr * 64 + i * 16 + l16) * 32 + q * 8];
#pragma unroll
    for (int j = 0; j < 4; ++j) bf[j] = *(const short8*)&BL[(wc * 64 + j * 16 + l16) * 32 + q * 8];
#pragma unroll
    for (int i = 0; i < 4; ++i)
#pragma unroll
      for (int j = 0; j < 4; ++j)
        acc[i][j] = __builtin_amdgcn_mfma_f32_16x16x32_bf16(af[i], bf[j], acc[i][j], 0, 0, 0);
  }
#pragma unroll
  for (int i = 0; i < 4; ++i)
#pragma unroll
    for (int j = 0; j < 4; ++j) {
      int gc = n0 + wc * 64 + j * 16 + l16;
      if (gc >= N) continue;
      float bb = bias ? bias[gc] : 0.f;
#pragma unroll
      for (int r = 0; r < 4; ++r) {
        int gr = m0 + wr * 64 + i * 16 + q * 4 + r;
        if (gr >= M) continue;
        float v = acc[i][j][r] + bb;
        if (flags & 1) v = fmaxf(v, 0.f);
        size_t orow = (size_t)gr;
        if (flags & 4) { int t = gr >> 7, b_ = gr & 127; orow = (size_t)b_ * 47 + t; }
        if (flags & 2) ((float*)Cout)[orow * (size_t)N + gc] = v;
        else ((ushort*)Cout)[orow * (size_t)N + gc] = f2bf(v);
      }
    }
}

// ---------------- fused 47-step recurrence, ONE dispatch, 64 blocks ----------------
#define NBLK 64
__device__ __forceinline__ void gridbar(int* bar, int bc) {
  __syncthreads();
  if (threadIdx.x == 0) {
    __threadfence();
    int a = __hip_atomic_fetch_add(&bar[0], 1, __ATOMIC_ACQ_REL, __HIP_MEMORY_SCOPE_AGENT) + 1;
    if (a == bc * NBLK) {
      __hip_atomic_fetch_add(&bar[1], 1, __ATOMIC_ACQ_REL, __HIP_MEMORY_SCOPE_AGENT);
    } else {
      while (__hip_atomic_load(&bar[1], __ATOMIC_ACQUIRE, __HIP_MEMORY_SCOPE_AGENT) < bc)
        __builtin_amdgcn_s_sleep(4);
    }
  }
  __syncthreads();
}

__global__ __launch_bounds__(256) void fused_loop(
    const ushort* __restrict__ featW1,   // (8192,512) bf16, row = b*64+l
    const ushort* __restrict__ features, // (8192,256) bf16
    const ushort* __restrict__ embA,     // (6016,256) bf16, row = t*128+b
    const ushort* __restrict__ W2T,      // (512,512) bf16 (col-major of W2)
    const float* __restrict__ b2,        // (512)
    const float* __restrict__ V,         // (512)
    const ushort* __restrict__ gruT,     // (1536,512) bf16 (col-major of gru_k)
    const float* __restrict__ grub0,     // (1536)
    const float* __restrict__ grub1,     // (1536)
    ushort* __restrict__ statesG,        // (48,128,512) bf16, slot 0 pre-zeroed
    float* __restrict__ hw2G,            // (128,512) fp32 scratch
    ushort* __restrict__ xG,             // (128,512) bf16 scratch: [ctx | emb]
    int* __restrict__ bar) {
  __shared__ float sLds[2][64];
  __shared__ float aLds[2][64];
  int wave = threadIdx.x >> 6, lane = threadIdx.x & 63;
  int q = lane >> 4, l16 = lane & 15;
  int bc = 0;
  for (int t = 0; t < 47; ++t) {
    // ---- phase 1: hw2G = statesG[t] @ W2T^T + b2 ; 256 16x16 tiles, 4/block ----
    {
      const ushort* Ht = statesG + (size_t)t * 65536;
      int tau = blockIdx.x * 4 + wave;   // 0..255
      int mi = tau >> 5, ni = tau & 31;
      const ushort* arow = Ht + (size_t)(mi * 16 + l16) * 512 + q * 8;
      const ushort* brow = W2T + (size_t)(ni * 16 + l16) * 512 + q * 8;
      f32x4 acc = (f32x4){0.f, 0.f, 0.f, 0.f};
#pragma unroll 4
      for (int k = 0; k < 512; k += 32)
        acc = __builtin_amdgcn_mfma_f32_16x16x32_bf16(
            *(const short8*)(arow + k), *(const short8*)(brow + k), acc, 0, 0, 0);
      float bb = b2[ni * 16 + l16];
#pragma unroll
      for (int r = 0; r < 4; ++r)
        hw2G[(size_t)(mi * 16 + q * 4 + r) * 512 + ni * 16 + l16] = acc[r] + bb;
    }
    gridbar(bar, ++bc);
    // ---- phase 2: scores -> softmax -> context ; block owns rows 2g, 2g+1 ----
    {
      int b = blockIdx.x * 2 + (threadIdx.x >> 7);
      int rem = threadIdx.x & 127, l = rem >> 1, part = rem & 1;
      const ushort* fw = featW1 + (size_t)(b * 64 + l) * 512 + part * 256;
      const float* hw = hw2G + (size_t)b * 512 + part * 256;
      const float* Vp = V + part * 256;
      float s = 0.f;
#pragma unroll 2
      for (int i = 0; i < 256; i += 8) {
        short8 f8 = *(const short8*)(fw + i);
        f32x4 h0 = *(const f32x4*)(hw + i);
        f32x4 h1 = *(const f32x4*)(hw + i + 4);
#pragma unroll
        for (int e = 0; e < 8; ++e) {
          float x = bf2f((ushort)f8[e]) + ((e < 4) ? h0[e] : h1[e - 4]);
          s += tanh_fast(x) * Vp[i + e];
        }
      }
      s += __shfl_xor(s, 1);
      int rb = threadIdx.x >> 7;
      if (part == 0) sLds[rb][l] = s;
      __syncthreads();
      if (threadIdx.x < 128) {
        int w = threadIdx.x >> 6, l2 = threadIdx.x & 63;
        float v = sLds[w][l2], m = v;
        for (int o = 32; o; o >>= 1) m = fmaxf(m, __shfl_xor(m, o));
        float e = __expf(v - m), ss = e;
        for (int o = 32; o; o >>= 1) ss += __shfl_xor(ss, o);
        aLds[w][l2] = e / ss;
      }
      __syncthreads();
      int e0 = (threadIdx.x & 127) * 2;
      int gb = blockIdx.x * 2 + rb;
      float c0 = 0.f, c1 = 0.f;
      const ushort* fbase = features + (size_t)gb * 64 * 256 + e0;
#pragma unroll 4
      for (int l2 = 0; l2 < 64; ++l2) {
        float aw = aLds[rb][l2];
        uint u32 = *(const uint*)(fbase + (size_t)l2 * 256);
        c0 += aw * bf2f((ushort)(u32 & 0xffff));
        c1 += aw * bf2f((ushort)(u32 >> 16));
      }
      xG[(size_t)gb * 512 + e0] = f2bf(c0);
      xG[(size_t)gb * 512 + e0 + 1] = f2bf(c1);
      *(uint*)(xG + (size_t)gb * 512 + 256 + e0) =
          *(const uint*)(embA + (size_t)t * 32768 + (size_t)gb * 256 + e0);
    }
    gridbar(bar, ++bc);
    // ---- phase 3: GRU: [ctx|emb] @ gruT^T, (z,r,h) triples in-register ----
    {
      int tau = blockIdx.x * 4 + wave;   // 0..255 = 8 m-tiles x 32 u-tiles
      int mi = tau >> 5, ui = tau & 31;
      const ushort* arow = xG + (size_t)(mi * 16 + l16) * 512 + q * 8;
      const ushort* bz = gruT + (size_t)(ui * 16 + l16) * 512 + q * 8;
      const ushort* br = gruT + (size_t)(512 + ui * 16 + l16) * 512 + q * 8;
      const ushort* bh = gruT + (size_t)(1024 + ui * 16 + l16) * 512 + q * 8;
      f32x4 az = (f32x4){0.f, 0.f, 0.f, 0.f};
      f32x4 ar = az, ah = az;
#pragma unroll 2
      for (int k = 0; k < 512; k += 32) {
        short8 af = *(const short8*)(arow + k);
        az = __builtin_amdgcn_mfma_f32_16x16x32_bf16(af, *(const short8*)(bz + k), az, 0, 0, 0);
        ar = __builtin_amdgcn_mfma_f32_16x16x32_bf16(af, *(const short8*)(br + k), ar, 0, 0, 0);
        ah = __builtin_amdgcn_mfma_f32_16x16x32_bf16(af, *(const short8*)(bh + k), ah, 0, 0, 0);
      }
      int u = ui * 16 + l16;
      float g0z = grub0[u], g0r = grub0[512 + u], g0h = grub0[1024 + u];
      float g1z = grub1[u], g1r = grub1[512 + u], g1h = grub1[1024 + u];
      ushort* outp = statesG + (size_t)(t + 1) * 65536;
#pragma unroll
      for (int r_ = 0; r_ < 4; ++r_) {
        float z = 1.f / (1.f + __expf(-(az[r_] + g0z + g1z)));
        float rr = 1.f / (1.f + __expf(-(ar[r_] + g0r + g1r)));
        float hh = tanh_fast(ah[r_] + g0h + rr * g1h);
        outp[(size_t)(mi * 16 + q * 4 + r_) * 512 + u] = f2bf((1.f - z) * hh);
      }
    }
    gridbar(bar, ++bc);
  }
}

extern "C" void kernel_launch(void* const* d_in, const int* in_sizes, int n_in,
                              void* d_out, int out_size, void* d_ws, size_t ws_size,
                              hipStream_t stream) {
  const float* img    = (const float*)d_in[0];
  const int*   target = (const int*)d_in[1];
  const float* W_fc   = (const float*)d_in[2];
  const float* b_fc   = (const float*)d_in[3];
  const float* W1     = (const float*)d_in[4];
  const float* b1     = (const float*)d_in[5];
  const float* W2     = (const float*)d_in[6];
  const float* b2     = (const float*)d_in[7];
  const float* V      = (const float*)d_in[8];
  const float* bV     = (const float*)d_in[9];  (void)bV; // constant shift, cancels in softmax
  const float* emb    = (const float*)d_in[10];
  const float* gru_k  = (const float*)d_in[11];
  /* d_in[12] = gru_rk: dead (h0 == 0 every step) */
  const float* gru_b  = (const float*)d_in[13];
  const float* fc1_w  = (const float*)d_in[14];
  const float* fc1_b  = (const float*)d_in[15];
  const float* fc2_w  = (const float*)d_in[16];
  const float* fc2_b  = (const float*)d_in[17];

  // ---- d_ws (~15.3 MB): transposed bf16 weights + fc1 output + barrier ----
  char* wsb = (char*)d_ws;
  size_t off = 0;
  auto alloc = [&](size_t bytes) {
    char* p = wsb + off;
    off += (bytes + 255) & ~(size_t)255;
    return p;
  };
  ushort* W_fcT  = (ushort*)alloc((size_t)256 * 2048 * 2);
  ushort* W1T    = (ushort*)alloc((size_t)512 * 256 * 2);
  ushort* W2T    = (ushort*)alloc((size_t)512 * 512 * 2);
  ushort* gruT   = (ushort*)alloc((size_t)1536 * 512 * 2);
  ushort* fc1T   = (ushort*)alloc((size_t)512 * 512 * 2);
  ushort* fc2T   = (ushort*)alloc((size_t)5120 * 512 * 2);  // padded to 5120 rows
  ushort* hid2ws = (ushort*)alloc((size_t)6016 * 512 * 2);
  int*    bar    = (int*)alloc(256);

  // ---- big bf16 intermediates inside d_out (fp32 out = 120.3 MB; 55.9 MB used).
  // All dead before the final fc2 GEMM, which reads only d_ws and overwrites all of d_out.
  char* ob = (char*)d_out;
  ushort* imgB     = (ushort*)(ob);                          // 33,554,432 B
  ushort* features = (ushort*)(ob + (size_t)33554432);       //  4,194,304 B
  ushort* featW1   = (ushort*)(ob + (size_t)37748736);       //  8,388,608 B
  ushort* statesG  = (ushort*)(ob + (size_t)46137344);       //  6,291,456 B
  ushort* embA     = (ushort*)(ob + (size_t)52428800);       //  3,080,192 B
  float*  hw2G     = (float*) (ob + (size_t)55508992);       //    262,144 B
  ushort* xG       = (ushort*)(ob + (size_t)55771136);       //    131,072 B

  // ---- prep: convert img, transpose weights, gather embeddings ----
  f2b_vec<<<8192, 256, 0, stream>>>(img, imgB, 8192 * 2048);
  dim3 tb(32, 8);
  transpose_f2b<<<dim3(8, 64), tb, 0, stream>>>(W_fc, W_fcT, 2048, 256);
  transpose_f2b<<<dim3(16, 8), tb, 0, stream>>>(W1, W1T, 256, 512);
  transpose_f2b<<<dim3(16, 16), tb, 0, stream>>>(W2, W2T, 512, 512);
  transpose_f2b<<<dim3(48, 16), tb, 0, stream>>>(gru_k, gruT, 512, 1536);
  transpose_f2b<<<dim3(16, 16), tb, 0, stream>>>(fc1_w, fc1T, 512, 512);
  transpose_f2b<<<dim3(157, 16), tb, 0, stream>>>(fc2_w, fc2T, 512, 5000);
  embed_gather<<<6016, 256, 0, stream>>>(target, emb, embA);

  // ---- encoder + attention-precompute GEMMs ----
  gemm_tile<<<dim3(2, 64), 256, 0, stream>>>(imgB, W_fcT, b_fc, features, 8192, 256, 2048, 1);
  gemm_tile<<<dim3(4, 64), 256, 0, stream>>>(features, W1T, b1, featW1, 8192, 512, 256, 0);

  // ---- recurrence: one dispatch ----
  hipMemsetAsync(statesG, 0, (size_t)128 * 512 * 2, stream);  // hidden_0 = 0
  hipMemsetAsync(bar, 0, 256, stream);
  fused_loop<<<NBLK, 256, 0, stream>>>(featW1, features, embA, W2T, b2, V,
                                       gruT, gru_b, gru_b + 1536,
                                       statesG, hw2G, xG, bar);

  // ---- fc1 + fc2 ----
  gemm_tile<<<dim3(4, 47), 256, 0, stream>>>(statesG + (size_t)65536, fc1T, fc1_b,
                                             hid2ws, 6016, 512, 512, 0);
  gemm_tile<<<dim3(40, 47), 256, 0, stream>>>(hid2ws, fc2T, fc2_b, d_out,
                                              6016, 5000, 512, 2 | 4);
}